// Round 1
// 84.910 us; speedup vs baseline: 1.0596x; 1.0596x over previous
//
#include <hip/hip_runtime.h>
#include <math.h>

#define NQ 4
#define DIM 16
#define BB 4
#define SS 512
#define EE 512
#define ROWS (BB * SS)   // 2048

typedef float f32x2 __attribute__((ext_vector_type(2)));

// tanh via exp: 1 - 2/(e^{2x}+1). Exact at saturation (x->±inf -> ±1),
// abs err ~1e-7 (vs libm tanhf ~25 branchy ops).
__device__ __forceinline__ float fast_tanh(float x) {
    float e = __expf(2.f * x);
    return fmaf(-2.f, __builtin_amdgcn_rcpf(e + 1.f), 1.f);
}

// ---------------------------------------------------------------------------
// Kernel 1 (fused): block 0 = circuit -> 81 trig-poly coefficients T;
// blocks 1..512 = qkv projections (4 rows per block, one wave per row).
// ---------------------------------------------------------------------------
__global__ __launch_bounds__(256) void k_prep(
    const float* __restrict__ x,
    const float* __restrict__ Wq, const float* __restrict__ bq,
    const float* __restrict__ Wk, const float* __restrict__ bk,
    const float* __restrict__ Wv, const float* __restrict__ bv,
    const float* __restrict__ qw,
    float* __restrict__ tq, float* __restrict__ tk, float* __restrict__ v,
    float* __restrict__ T_out) {
    if (blockIdx.x == 0) {
        // ---------------- circuit path (one block) ----------------
        __shared__ float sG[8][8];
        __shared__ float Ur[DIM][DIM];
        __shared__ float Ui[DIM][DIM];
        __shared__ float sMr[256];
        int t = threadIdx.x;
        if (t < 8) {   // one Rot gate per thread
            float a = qw[t * 3 + 0] * 0.5f;
            float b = qw[t * 3 + 1] * 0.5f;
            float c = qw[t * 3 + 2] * 0.5f;
            float sa = __sinf(a), ca = __cosf(a);
            float sb = __sinf(b), cb = __cosf(b);
            float sc = __sinf(c), cc = __cosf(c);
            float m00r = cb * ca, m00i = sb * sa;
            float m01r = -sb * ca, m01i = -cb * sa;
            float m10r = sb * ca, m10i = -cb * sa;
            float m11r = cb * ca, m11i = -sb * sa;
            sG[t][0] = cc * m00r + sc * m00i;
            sG[t][1] = cc * m00i - sc * m00r;
            sG[t][2] = cc * m01r + sc * m01i;
            sG[t][3] = cc * m01i - sc * m01r;
            sG[t][4] = cc * m10r - sc * m10i;
            sG[t][5] = cc * m10i + sc * m10r;
            sG[t][6] = cc * m11r - sc * m11i;
            sG[t][7] = cc * m11i + sc * m11r;
        }
        __syncthreads();
        if (t < DIM) {   // simulate basis column t
            float vr[DIM], vi[DIM];
#pragma unroll
            for (int i = 0; i < DIM; ++i) { vr[i] = (i == t) ? 1.f : 0.f; vi[i] = 0.f; }
#pragma unroll
            for (int gi = 0; gi < 8; ++gi) {
                int w = gi & 3;
                float g00r = sG[gi][0], g00i = sG[gi][1];
                float g01r = sG[gi][2], g01i = sG[gi][3];
                float g10r = sG[gi][4], g10i = sG[gi][5];
                float g11r = sG[gi][6], g11i = sG[gi][7];
                int mask = 1 << (3 - w);
#pragma unroll
                for (int idx = 0; idx < DIM; ++idx) {
                    if (idx & mask) continue;
                    int i1 = idx | mask;
                    float r0 = vr[idx], i0 = vi[idx], r1 = vr[i1], i1v = vi[i1];
                    vr[idx] = g00r * r0 - g00i * i0 + g01r * r1 - g01i * i1v;
                    vi[idx] = g00r * i0 + g00i * r0 + g01r * i1v + g01i * r1;
                    vr[i1]  = g10r * r0 - g10i * i0 + g11r * r1 - g11i * i1v;
                    vi[i1]  = g10r * i0 + g10i * r0 + g11r * i1v + g11i * r1;
                }
                if (w == 3) {  // CNOT chain (0,1),(1,2),(2,3),(3,0)
                    const int cwire[4] = {0, 1, 2, 3};
                    const int twire[4] = {1, 2, 3, 0};
#pragma unroll
                    for (int e = 0; e < 4; ++e) {
                        int cmask = 1 << (3 - cwire[e]);
                        int tmask = 1 << (3 - twire[e]);
                        float nr[DIM], ni[DIM];
#pragma unroll
                        for (int idx = 0; idx < DIM; ++idx) {
                            int src = (idx & cmask) ? (idx ^ tmask) : idx;
                            nr[idx] = vr[src]; ni[idx] = vi[src];
                        }
#pragma unroll
                        for (int idx = 0; idx < DIM; ++idx) { vr[idx] = nr[idx]; vi[idx] = ni[idx]; }
                    }
                }
            }
#pragma unroll
            for (int i = 0; i < DIM; ++i) { Ur[i][t] = vr[i]; Ui[i][t] = vi[i]; }
        }
        __syncthreads();
        {
            int k = t >> 4, l = t & 15;
            float acc = 0.f;
#pragma unroll
            for (int idx = 0; idx < DIM; ++idx) {
                float z = 4.f - 2.f * (float)__popc(idx);
                acc += z * (Ur[idx][k] * Ur[idx][l] + Ui[idx][k] * Ui[idx][l]);
            }
            sMr[t] = acc;
        }
        __syncthreads();
        if (t < 81) {
            int e3 = t % 3, e2 = (t / 3) % 3, e1 = (t / 9) % 3, e0 = t / 27;
            int xm = ((e0 == 2) << 3) | ((e1 == 2) << 2) | ((e2 == 2) << 1) | (int)(e3 == 2);
            int sm = ((e0 == 1) << 3) | ((e1 == 1) << 2) | ((e2 == 1) << 1) | (int)(e3 == 1);
            float acc = 0.f;
#pragma unroll
            for (int K = 0; K < DIM; ++K) {
                float s = (__popc(K & sm) & 1) ? -1.f : 1.f;
                acc += s * sMr[K * 16 + (K ^ xm)];
            }
            T_out[((e0 * 3 + e1) * 3 + e2) * 4 + e3] = acc * (1.f / 32.f);
        }
        if (t < 27) T_out[t * 4 + 3] = 0.f;
    } else {
        // ---------------- qkv path: one wave per row, packed-f32 accumulators ----
        int row = (blockIdx.x - 1) * 4 + (threadIdx.x >> 6);
        int lane = threadIdx.x & 63;
        const float4* xr4 = (const float4*)(x + (size_t)row * EE);
        f32x2 aq0 = {0.f, 0.f}, aq1 = {0.f, 0.f};
        f32x2 ak0 = {0.f, 0.f}, ak1 = {0.f, 0.f};
        f32x2 av0 = {0.f, 0.f}, av1 = {0.f, 0.f};
#pragma unroll
        for (int h = 0; h < 2; ++h) {
            int e4 = lane + h * 64;          // float4 index; e = e4*4
            float4 xv = xr4[e4];
            float xc[4] = {xv.x, xv.y, xv.z, xv.w};
#pragma unroll
            for (int c = 0; c < 4; ++c) {
                int e = e4 * 4 + c;
                const f32x2* wq2 = (const f32x2*)(Wq + e * 4);
                const f32x2* wk2 = (const f32x2*)(Wk + e * 4);
                const f32x2* wv2 = (const f32x2*)(Wv + e * 4);
                f32x2 xb = {xc[c], xc[c]};
                aq0 += xb * wq2[0]; aq1 += xb * wq2[1];
                ak0 += xb * wk2[0]; ak1 += xb * wk2[1];
                av0 += xb * wv2[0]; av1 += xb * wv2[1];
            }
        }
#pragma unroll
        for (int off = 32; off > 0; off >>= 1) {
            f32x2 t;
            t.x = __shfl_down(aq0.x, off, 64); t.y = __shfl_down(aq0.y, off, 64); aq0 += t;
            t.x = __shfl_down(aq1.x, off, 64); t.y = __shfl_down(aq1.y, off, 64); aq1 += t;
            t.x = __shfl_down(ak0.x, off, 64); t.y = __shfl_down(ak0.y, off, 64); ak0 += t;
            t.x = __shfl_down(ak1.x, off, 64); t.y = __shfl_down(ak1.y, off, 64); ak1 += t;
            t.x = __shfl_down(av0.x, off, 64); t.y = __shfl_down(av0.y, off, 64); av0 += t;
            t.x = __shfl_down(av1.x, off, 64); t.y = __shfl_down(av1.y, off, 64); av1 += t;
        }
        if (lane == 0) {
            tq[row * 4 + 0] = fast_tanh(fast_tanh(aq0.x + bq[0]));
            tq[row * 4 + 1] = fast_tanh(fast_tanh(aq0.y + bq[1]));
            tq[row * 4 + 2] = fast_tanh(fast_tanh(aq1.x + bq[2]));
            tq[row * 4 + 3] = fast_tanh(fast_tanh(aq1.y + bq[3]));
            tk[row * 4 + 0] = fast_tanh(fast_tanh(ak0.x + bk[0]));
            tk[row * 4 + 1] = fast_tanh(fast_tanh(ak0.y + bk[1]));
            tk[row * 4 + 2] = fast_tanh(fast_tanh(ak1.x + bk[2]));
            tk[row * 4 + 3] = fast_tanh(fast_tanh(ak1.y + bk[3]));
            v[row * 4 + 0] = av0.x + bv[0];
            v[row * 4 + 1] = av0.y + bv[1];
            v[row * 4 + 2] = av1.x + bv[2];
            v[row * 4 + 3] = av1.y + bv[3];
        }
    }
}

// ---------------------------------------------------------------------------
// Kernel 2: one block (256 threads) per query row; thread handles j, j+256.
// The two j-rows are packed into f32x2 -> v_pk_fma_f32. T read via uniform
// scalar loads (s_load through K$), no LDS staging. rcp-based fast divides
// (denominator provably in [0.42, 1.58]).
// ---------------------------------------------------------------------------
__global__ __launch_bounds__(256) void k_attn(
    const float* __restrict__ tq, const float* __restrict__ tk,
    const float* __restrict__ v, const float* __restrict__ Tg,
    const float* __restrict__ Wout, const float* __restrict__ bout,
    float* __restrict__ attn_out, float* __restrict__ out) {
    int row = blockIdx.x;        // b*S + i
    int b = row >> 9;
    int tid = threadIdx.x;
    int wid = tid >> 6, lane = tid & 63;
    int j0 = tid, j1 = tid + 256;

    __shared__ float red[4][5];

    const float4 q4 = *(const float4*)(tq + row * 4);  // wave-uniform
    const float4 ka = *(const float4*)(tk + (size_t)(b * SS + j0) * 4);
    const float4 kb = *(const float4*)(tk + (size_t)(b * SS + j1) * 4);

    // t_w = tanh(q_w + k_w) via addition identity on pre-tanh'd values.
    // |q|,|k| <= tanh(1)=0.7616 -> 1+qk in [0.42,1.58] -> raw v_rcp safe.
    float t0a = (q4.x + ka.x) * __builtin_amdgcn_rcpf(fmaf(q4.x, ka.x, 1.f));
    float t1a = (q4.y + ka.y) * __builtin_amdgcn_rcpf(fmaf(q4.y, ka.y, 1.f));
    float t2a = (q4.z + ka.z) * __builtin_amdgcn_rcpf(fmaf(q4.z, ka.z, 1.f));
    float t3a = (q4.w + ka.w) * __builtin_amdgcn_rcpf(fmaf(q4.w, ka.w, 1.f));
    float t0b = (q4.x + kb.x) * __builtin_amdgcn_rcpf(fmaf(q4.x, kb.x, 1.f));
    float t1b = (q4.y + kb.y) * __builtin_amdgcn_rcpf(fmaf(q4.y, kb.y, 1.f));
    float t2b = (q4.z + kb.z) * __builtin_amdgcn_rcpf(fmaf(q4.z, kb.z, 1.f));
    float t3b = (q4.w + kb.w) * __builtin_amdgcn_rcpf(fmaf(q4.w, kb.w, 1.f));

    // packed {a,b} basis values
    f32x2 u0[3], u1[3], u2[3];
    u0[0] = (f32x2){1.f, 1.f}; u1[0] = (f32x2){1.f, 1.f}; u2[0] = (f32x2){1.f, 1.f};
    u0[1] = (f32x2){__cosf(t0a), __cosf(t0b)};
    u0[2] = (f32x2){__sinf(t0a), __sinf(t0b)};
    u1[1] = (f32x2){__cosf(t1a), __cosf(t1b)};
    u1[2] = (f32x2){__sinf(t1a), __sinf(t1b)};
    u2[1] = (f32x2){__cosf(t2a), __cosf(t2b)};
    u2[2] = (f32x2){__sinf(t2a), __sinf(t2b)};
    f32x2 c3 = (f32x2){__cosf(t3a), __cosf(t3b)};
    f32x2 s3 = (f32x2){__sinf(t3a), __sinf(t3b)};

    f32x2 sc = {0.f, 0.f};
#pragma unroll
    for (int e0 = 0; e0 < 3; ++e0) {
        f32x2 a1 = {0.f, 0.f};
#pragma unroll
        for (int e1 = 0; e1 < 3; ++e1) {
            f32x2 a2 = {0.f, 0.f};
#pragma unroll
            for (int e2 = 0; e2 < 3; ++e2) {
                int idx = ((e0 * 3 + e1) * 3 + e2) * 4;   // compile-time const
                float Tx = Tg[idx + 0];                   // uniform -> s_load
                float Ty = Tg[idx + 1];
                float Tz = Tg[idx + 2];
                f32x2 ia = (f32x2){Tx, Tx} + c3 * (f32x2){Ty, Ty} + s3 * (f32x2){Tz, Tz};
                a2 += u2[e2] * ia;
            }
            a1 += u1[e1] * a2;
        }
        sc += u0[e0] * a1;
    }

    // |sc| <= 2 (||amp||=1, ||M||_2 <= 4, /2 scale) -> no max subtraction needed
    float ex_a = __expf(sc.x);
    float ex_b = __expf(sc.y);

    const float4 va = *(const float4*)(v + (size_t)(b * SS + j0) * 4);
    const float4 vb = *(const float4*)(v + (size_t)(b * SS + j1) * 4);
    float vals[5];
    vals[0] = ex_a + ex_b;
    vals[1] = fmaf(ex_a, va.x, ex_b * vb.x);
    vals[2] = fmaf(ex_a, va.y, ex_b * vb.y);
    vals[3] = fmaf(ex_a, va.z, ex_b * vb.z);
    vals[4] = fmaf(ex_a, va.w, ex_b * vb.w);
#pragma unroll
    for (int off = 32; off > 0; off >>= 1) {
#pragma unroll
        for (int c = 0; c < 5; ++c) vals[c] += __shfl_xor(vals[c], off, 64);
    }
    if (lane == 0) {
#pragma unroll
        for (int c = 0; c < 5; ++c) red[wid][c] = vals[c];
    }
    __syncthreads();

    float tot = red[0][0] + red[1][0] + red[2][0] + red[3][0];
    float inv = 1.f / tot;

    attn_out[(size_t)row * SS + j0] = ex_a * inv;
    attn_out[(size_t)row * SS + j1] = ex_b * inv;

    float a0 = (red[0][1] + red[1][1] + red[2][1] + red[3][1]) * inv;
    float a1 = (red[0][2] + red[1][2] + red[2][2] + red[3][2]) * inv;
    float a2 = (red[0][3] + red[1][3] + red[2][3] + red[3][3]) * inv;
    float a3 = (red[0][4] + red[1][4] + red[2][4] + red[3][4]) * inv;

    // fused output projection: out[row, e] = sum_w a_w * Wout[w,e] + bout[e]
    int e = tid * 2;
    float2 w0 = *(const float2*)(Wout + 0 * EE + e);
    float2 w1 = *(const float2*)(Wout + 1 * EE + e);
    float2 w2 = *(const float2*)(Wout + 2 * EE + e);
    float2 w3 = *(const float2*)(Wout + 3 * EE + e);
    float2 bb = *(const float2*)(bout + e);
    float2 o;
    o.x = fmaf(a0, w0.x, fmaf(a1, w1.x, fmaf(a2, w2.x, fmaf(a3, w3.x, bb.x))));
    o.y = fmaf(a0, w0.y, fmaf(a1, w1.y, fmaf(a2, w2.y, fmaf(a3, w3.y, bb.y))));
    *(float2*)(out + (size_t)row * EE + e) = o;
}

extern "C" void kernel_launch(void* const* d_in, const int* in_sizes, int n_in,
                              void* d_out, int out_size, void* d_ws, size_t ws_size,
                              hipStream_t stream) {
    const float* x    = (const float*)d_in[0];
    const float* Wq   = (const float*)d_in[1];
    const float* bq   = (const float*)d_in[2];
    const float* Wk   = (const float*)d_in[3];
    const float* bk   = (const float*)d_in[4];
    const float* Wv   = (const float*)d_in[5];
    const float* bv   = (const float*)d_in[6];
    const float* qw   = (const float*)d_in[7];
    const float* Wout = (const float*)d_in[8];
    const float* bout = (const float*)d_in[9];

    float* out  = (float*)d_out;                 // [B,S,E]
    float* attn = out + (size_t)ROWS * EE;       // [B,S,S]

    float* ws  = (float*)d_ws;
    float* T   = ws;                  // 108 floats (pad to 128)
    float* tq  = ws + 128;            // 8192
    float* tk  = tq + ROWS * 4;       // 8192
    float* v   = tk + ROWS * 4;       // 8192

    k_prep<<<1 + ROWS / 4, 256, 0, stream>>>(x, Wq, bq, Wk, bk, Wv, bv, qw, tq, tk, v, T);
    k_attn<<<ROWS, 256, 0, stream>>>(tq, tk, v, T, Wout, bout, attn, out);
}